// Round 3
// baseline (2492.764 us; speedup 1.0000x reference)
//
#include <hip/hip_runtime.h>
#include <hip/hip_bf16.h>
#include <cstdint>
#include <cstddef>

// ---------------------------------------------------------------------------
// Swin block, MI355X. Pipeline:
//   transpose weights -> bf16 (N x K)
//   LN1 (+roll+window gather) -> h bf16 [M][512]   (M = 100352, window-major)
//   GEMM qkv: h @ wqkvT -> qkv bf16 [M][1536]
//   attention: per (window, head) wave, MFMA 16x16x32, bias+mask on the fly
//   GEMM proj (+window-reverse +roll +residual) -> y fp32 in d_out
//   LN2 -> h2 bf16 [M][512]
//   GEMM mlp1 (+GELU exact) -> hid bf16 [M][2048]  (aliases qkv+attno region)
//   GEMM mlp2 (+bias +residual y) -> d_out fp32
// ---------------------------------------------------------------------------

using s8v = __attribute__((ext_vector_type(8))) short;   // 8 x bf16 fragment
using f4v = __attribute__((ext_vector_type(4))) float;   // MFMA accumulator

__device__ __forceinline__ short f2bf(float f) {
  union { __hip_bfloat16 h; short s; } u;
  u.h = __float2bfloat16(f);
  return u.s;
}

__device__ __forceinline__ f4v mfma16(s8v a, s8v b, f4v c) {
  return __builtin_amdgcn_mfma_f32_16x16x32_bf16(a, b, c, 0, 0, 0);
}

__device__ __forceinline__ f4v zero_f4() {
  f4v z; z[0] = 0.f; z[1] = 0.f; z[2] = 0.f; z[3] = 0.f; return z;
}
__device__ __forceinline__ s8v zero_s8() {
  s8v z;
#pragma unroll
  for (int i = 0; i < 8; ++i) z[i] = 0;
  return z;
}

// ---------------------------------------------------------------------------
// weight transpose fp32[K][N] -> bf16[N][K]
// ---------------------------------------------------------------------------
__global__ __launch_bounds__(256) void transpose_w(const float* __restrict__ in,
                                                   short* __restrict__ outT,
                                                   int K, int N) {
  int idx = blockIdx.x * 256 + threadIdx.x;
  if (idx >= K * N) return;
  int k = idx / N, n = idx - k * N;
  outT[(size_t)n * K + k] = f2bf(in[idx]);
}

// ---------------------------------------------------------------------------
// LayerNorm over C=512; one token per wave, 4 waves/block.
// gather=1: m is window-major row -> gather from rolled image position.
// ---------------------------------------------------------------------------
__global__ __launch_bounds__(256) void ln_kernel(const float* __restrict__ xin,
                                                 const float* __restrict__ g,
                                                 const float* __restrict__ bt,
                                                 short* __restrict__ outh,
                                                 int gather) {
  const int wid = threadIdx.x >> 6, lane = threadIdx.x & 63;
  const int m = blockIdx.x * 4 + wid;
  size_t src;
  if (gather) {
    int w = m / 49, n = m - w * 49;
    int b = w >> 6, wh = (w >> 3) & 7, ww = w & 7;
    int i = n / 7, j = n - i * 7;
    int r = wh * 7 + i + 3; if (r >= 56) r -= 56;
    int c = ww * 7 + j + 3; if (c >= 56) c -= 56;
    src = (size_t)b * 3136 + r * 56 + c;
  } else {
    src = m;
  }
  const float4* xp = (const float4*)(xin + src * 512) + lane * 2;
  float4 u0 = xp[0], u1 = xp[1];
  float vs[8] = {u0.x, u0.y, u0.z, u0.w, u1.x, u1.y, u1.z, u1.w};
  float s = 0.f;
#pragma unroll
  for (int e = 0; e < 8; ++e) s += vs[e];
#pragma unroll
  for (int msk = 1; msk < 64; msk <<= 1) s += __shfl_xor(s, msk, 64);
  const float mean = s * (1.0f / 512.0f);
  float ss = 0.f;
#pragma unroll
  for (int e = 0; e < 8; ++e) { float d = vs[e] - mean; ss += d * d; }
#pragma unroll
  for (int msk = 1; msk < 64; msk <<= 1) ss += __shfl_xor(ss, msk, 64);
  const float rstd = rsqrtf(ss * (1.0f / 512.0f) + 1e-5f);
  const float4* gp = (const float4*)g + lane * 2;
  const float4* bp = (const float4*)bt + lane * 2;
  float4 g0 = gp[0], g1 = gp[1], b0 = bp[0], b1 = bp[1];
  float gs[8] = {g0.x, g0.y, g0.z, g0.w, g1.x, g1.y, g1.z, g1.w};
  float bs[8] = {b0.x, b0.y, b0.z, b0.w, b1.x, b1.y, b1.z, b1.w};
  s8v o;
#pragma unroll
  for (int e = 0; e < 8; ++e) o[e] = f2bf((vs[e] - mean) * rstd * gs[e] + bs[e]);
  *(s8v*)(outh + (size_t)m * 512 + lane * 8) = o;
}

// ---------------------------------------------------------------------------
// bf16 GEMM, m97 structure: 128x128 tile, BK=64, 4 waves (2x2 of 64x64),
// global_load_lds width 16, 16x16x32 MFMA. A[M][K], BT[N][K], both bf16.
// EPI: 0=qkv(bias->bf16) 1=proj(bias+window-reverse+residual->fp32)
//      2=gelu(bias+erf gelu->bf16) 3=res(bias+residual->fp32)
// ---------------------------------------------------------------------------
template <int EPI>
__global__ __launch_bounds__(256) void gemm_bt(const short* __restrict__ A,
                                               const short* __restrict__ BT,
                                               const float* __restrict__ bias,
                                               short* __restrict__ outb,
                                               const float* resid,
                                               float* outf,
                                               int K, int N) {
  __shared__ short As[128 * 64];
  __shared__ short Bs[128 * 64];
  const int tid = threadIdx.x;
  const int wid = tid >> 6, lane = tid & 63;
  const int lr = lane & 15, hi = lane >> 4;
  const int brow = blockIdx.y, bcol = blockIdx.x;
  const int r0 = (wid >> 1) * 64, c0 = (wid & 1) * 64;
  const int srow = lane >> 3, scol = (lane & 7) * 8;

  f4v acc[4][4];
#pragma unroll
  for (int a = 0; a < 4; ++a)
#pragma unroll
    for (int b = 0; b < 4; ++b) acc[a][b] = zero_f4();

  const short* Ab = A + (size_t)brow * 128 * K;
  const short* Bb = BT + (size_t)bcol * 128 * K;

  for (int k0 = 0; k0 < K; k0 += 64) {
#pragma unroll
    for (int i = 0; i < 4; ++i) {
      const int chunk = wid * 4 + i;
      const int row = chunk * 8 + srow;
      __builtin_amdgcn_global_load_lds(
          (const __attribute__((address_space(1))) void*)(Ab + (size_t)row * K + k0 + scol),
          (__attribute__((address_space(3))) void*)(As + chunk * 512), 16, 0, 0);
      __builtin_amdgcn_global_load_lds(
          (const __attribute__((address_space(1))) void*)(Bb + (size_t)row * K + k0 + scol),
          (__attribute__((address_space(3))) void*)(Bs + chunk * 512), 16, 0, 0);
    }
    __syncthreads();
#pragma unroll
    for (int kk = 0; kk < 64; kk += 32) {
      s8v af[4], bfr[4];
#pragma unroll
      for (int mi = 0; mi < 4; ++mi)
        af[mi] = *(const s8v*)(As + (r0 + mi * 16 + lr) * 64 + kk + hi * 8);
#pragma unroll
      for (int ni = 0; ni < 4; ++ni)
        bfr[ni] = *(const s8v*)(Bs + (c0 + ni * 16 + lr) * 64 + kk + hi * 8);
#pragma unroll
      for (int mi = 0; mi < 4; ++mi)
#pragma unroll
        for (int ni = 0; ni < 4; ++ni)
          acc[mi][ni] = mfma16(af[mi], bfr[ni], acc[mi][ni]);
    }
    __syncthreads();
  }

#pragma unroll
  for (int mi = 0; mi < 4; ++mi) {
#pragma unroll
    for (int ni = 0; ni < 4; ++ni) {
      const int col = bcol * 128 + c0 + ni * 16 + lr;
      const float bv = bias[col];
      f4v v = acc[mi][ni];
#pragma unroll
      for (int j = 0; j < 4; ++j) {
        const int row = brow * 128 + r0 + mi * 16 + hi * 4 + j;
        float val = v[j] + bv;
        if constexpr (EPI == 0) {
          outb[(size_t)row * N + col] = f2bf(val);
        } else if constexpr (EPI == 1) {
          int w = row / 49, n = row - w * 49;
          int b = w >> 6, wh = (w >> 3) & 7, ww = w & 7;
          int ii = n / 7, jj = n - ii * 7;
          int r = wh * 7 + ii + 3; if (r >= 56) r -= 56;
          int c = ww * 7 + jj + 3; if (c >= 56) c -= 56;
          size_t tok = (size_t)b * 3136 + r * 56 + c;
          outf[tok * 512 + col] = resid[tok * 512 + col] + val;
        } else if constexpr (EPI == 2) {
          float gv = 0.5f * val * (1.0f + erff(val * 0.70710678118654752f));
          outb[(size_t)row * N + col] = f2bf(gv);
        } else {
          outf[(size_t)row * 512 + col] = resid[(size_t)row * 512 + col] + val;
        }
      }
    }
  }
}

// ---------------------------------------------------------------------------
// Window attention: one wave per (window, head). N=49 padded to 64.
// scores = QK^T * hd^-0.5 + rel_bias + shift_mask ; softmax ; out = P @ V.
// ---------------------------------------------------------------------------
__device__ __forceinline__ int regof(int v) { return (v < 49) ? 0 : ((v < 53) ? 1 : 2); }

__global__ __launch_bounds__(64) void attn_kernel(const short* __restrict__ qkv,
                                                  const float* __restrict__ btab,
                                                  short* __restrict__ attno) {
  __shared__ short P[64 * 72];   // probs, bf16, padded stride 72
  __shared__ short Vt[32 * 72];  // V transposed [d][key], padded
  const int lane = threadIdx.x;
  const int w = blockIdx.x >> 4, head = blockIdx.x & 15;
  const int wh = (w >> 3) & 7, ww = w & 7;
  const int lr = lane & 15, hi = lane >> 4;

  // Q / K fragments straight from global (A-frag: row=lr, k=hi*8..+8)
  s8v qf[4], kf[4];
#pragma unroll
  for (int t = 0; t < 4; ++t) {
    int row = t * 16 + lr;
    qf[t] = zero_s8();
    kf[t] = zero_s8();
    if (row < 49) {
      const short* base = qkv + (size_t)(w * 49 + row) * 1536 + head * 32 + hi * 8;
      qf[t] = *(const s8v*)base;
      kf[t] = *(const s8v*)(base + 512);
    }
  }

  f4v s[4][4];
  const f4v zacc = zero_f4();
#pragma unroll
  for (int qt = 0; qt < 4; ++qt)
#pragma unroll
    for (int kt = 0; kt < 4; ++kt) s[qt][kt] = mfma16(qf[qt], kf[kt], zacc);

  // scale + relative-position bias + shift mask
  const float scale = 0.17677669529663687f;  // 1/sqrt(32)
  int ki_[4], kj_[4], labk_[4], kvalid[4];
#pragma unroll
  for (int kt = 0; kt < 4; ++kt) {
    int k = kt * 16 + lr;
    kvalid[kt] = (k < 49);
    int ki = k / 7, kj = k - ki * 7;
    ki_[kt] = ki; kj_[kt] = kj;
    labk_[kt] = regof(wh * 7 + ki) * 3 + regof(ww * 7 + kj);
  }
#pragma unroll
  for (int qt = 0; qt < 4; ++qt) {
#pragma unroll
    for (int j = 0; j < 4; ++j) {
      int q = qt * 16 + hi * 4 + j;
      int qvalid = (q < 49);
      int qi = q / 7, qj = q - qi * 7;
      int labq = regof(wh * 7 + qi) * 3 + regof(ww * 7 + qj);
#pragma unroll
      for (int kt = 0; kt < 4; ++kt) {
        float val = s[qt][kt][j] * scale;
        if (qvalid && kvalid[kt]) {
          int idx = (qi - ki_[kt] + 6) * 13 + (qj - kj_[kt] + 6);
          val += btab[idx * 16 + head];
          if (labq != labk_[kt]) val -= 100.f;
        }
        if (!kvalid[kt]) val = -1e30f;
        s[qt][kt][j] = val;
      }
    }
  }

  // softmax per row (row lives in 16 lanes sharing hi, 4 regs over kt)
#pragma unroll
  for (int qt = 0; qt < 4; ++qt) {
#pragma unroll
    for (int j = 0; j < 4; ++j) {
      float mx = fmaxf(fmaxf(s[qt][0][j], s[qt][1][j]), fmaxf(s[qt][2][j], s[qt][3][j]));
#pragma unroll
      for (int msk = 1; msk < 16; msk <<= 1) mx = fmaxf(mx, __shfl_xor(mx, msk, 64));
      float p[4], sum = 0.f;
#pragma unroll
      for (int kt = 0; kt < 4; ++kt) { p[kt] = __expf(s[qt][kt][j] - mx); sum += p[kt]; }
#pragma unroll
      for (int msk = 1; msk < 16; msk <<= 1) sum += __shfl_xor(sum, msk, 64);
      float inv = 1.f / sum;
      int q = qt * 16 + hi * 4 + j;
#pragma unroll
      for (int kt = 0; kt < 4; ++kt) P[q * 72 + kt * 16 + lr] = f2bf(p[kt] * inv);
    }
  }

  // V -> LDS transposed [d][key]
  for (int idx = lane; idx < 2048; idx += 64) {
    int key = idx >> 5, d = idx & 31;
    short v = 0;
    if (key < 49) v = qkv[(size_t)(w * 49 + key) * 1536 + 1024 + head * 32 + d];
    Vt[d * 72 + key] = v;
  }
  __syncthreads();

  // PV: P[64x64] @ V[64x32]
  f4v o[4][2];
#pragma unroll
  for (int at = 0; at < 4; ++at)
#pragma unroll
    for (int dt = 0; dt < 2; ++dt) o[at][dt] = zero_f4();
#pragma unroll
  for (int ks = 0; ks < 2; ++ks) {
    s8v pa[4], vb[2];
#pragma unroll
    for (int at = 0; at < 4; ++at)
      pa[at] = *(const s8v*)(P + (at * 16 + lr) * 72 + ks * 32 + hi * 8);
#pragma unroll
    for (int dt = 0; dt < 2; ++dt)
      vb[dt] = *(const s8v*)(Vt + (dt * 16 + lr) * 72 + ks * 32 + hi * 8);
#pragma unroll
    for (int at = 0; at < 4; ++at)
#pragma unroll
      for (int dt = 0; dt < 2; ++dt) o[at][dt] = mfma16(pa[at], vb[dt], o[at][dt]);
  }

#pragma unroll
  for (int at = 0; at < 4; ++at)
#pragma unroll
    for (int dt = 0; dt < 2; ++dt)
#pragma unroll
      for (int j = 0; j < 4; ++j) {
        int q = at * 16 + hi * 4 + j;
        if (q < 49)
          attno[(size_t)(w * 49 + q) * 512 + head * 32 + dt * 16 + lr] = f2bf(o[at][dt][j]);
      }
}

// ---------------------------------------------------------------------------
extern "C" void kernel_launch(void* const* d_in, const int* in_sizes, int n_in,
                              void* d_out, int out_size, void* d_ws, size_t ws_size,
                              hipStream_t stream) {
  const float* x      = (const float*)d_in[0];
  const float* w_qkv  = (const float*)d_in[1];
  const float* b_qkv  = (const float*)d_in[2];
  const float* w_proj = (const float*)d_in[3];
  const float* b_proj = (const float*)d_in[4];
  const float* btab   = (const float*)d_in[5];
  const float* ln1g   = (const float*)d_in[6];
  const float* ln1b   = (const float*)d_in[7];
  const float* ln2g   = (const float*)d_in[8];
  const float* ln2b   = (const float*)d_in[9];
  const float* w1     = (const float*)d_in[10];
  const float* b1     = (const float*)d_in[11];
  const float* w2     = (const float*)d_in[12];
  const float* b2     = (const float*)d_in[13];
  float* out = (float*)d_out;

  // workspace layout (bytes):
  //   0        wqkvT  [1536][512] bf16   (1,572,864)
  //   1572864  wprojT [512][512]         (524,288)
  //   2097152  w1T    [2048][512]        (2,097,152)
  //   4194304  w2T    [512][2048]        (2,097,152)
  //   6291456  bufH   [M][512]   bf16    (102,760,448)  h, then h2
  //   109051904 qkv   [M][1536]  bf16    (308,281,344)  \ aliased by
  //   417333248 attno [M][512]   bf16    (102,760,448)  / hid [M][2048]
  //   total 520,093,696
  char* ws = (char*)d_ws;
  short* wqkvT  = (short*)(ws + 0);
  short* wprojT = (short*)(ws + 1572864);
  short* w1T    = (short*)(ws + 2097152);
  short* w2T    = (short*)(ws + 4194304);
  short* bufH   = (short*)(ws + 6291456);
  short* qkvb   = (short*)(ws + 109051904);
  short* attno  = (short*)(ws + 417333248);
  short* hid    = qkvb;  // alias: qkv+attno dead when MLP1 writes hid

  transpose_w<<<dim3(3072), 256, 0, stream>>>(w_qkv, wqkvT, 512, 1536);
  transpose_w<<<dim3(1024), 256, 0, stream>>>(w_proj, wprojT, 512, 512);
  transpose_w<<<dim3(4096), 256, 0, stream>>>(w1, w1T, 512, 2048);
  transpose_w<<<dim3(4096), 256, 0, stream>>>(w2, w2T, 2048, 512);

  ln_kernel<<<dim3(25088), 256, 0, stream>>>(x, ln1g, ln1b, bufH, 1);
  gemm_bt<0><<<dim3(12, 784), 256, 0, stream>>>(bufH, wqkvT, b_qkv, qkvb, nullptr, nullptr, 512, 1536);
  attn_kernel<<<dim3(32768), 64, 0, stream>>>(qkvb, btab, attno);
  gemm_bt<1><<<dim3(4, 784), 256, 0, stream>>>(attno, wprojT, b_proj, nullptr, x, out, 512, 512);
  ln_kernel<<<dim3(25088), 256, 0, stream>>>(out, ln2g, ln2b, bufH, 0);
  gemm_bt<2><<<dim3(16, 784), 256, 0, stream>>>(bufH, w1T, b1, hid, nullptr, nullptr, 512, 2048);
  gemm_bt<3><<<dim3(4, 784), 256, 0, stream>>>(hid, w2T, b2, nullptr, out, out, 2048, 512);
}

// Round 4
// 2426.481 us; speedup vs baseline: 1.0273x; 1.0273x over previous
//
#include <hip/hip_runtime.h>
#include <hip/hip_bf16.h>
#include <cstdint>
#include <cstddef>

// ---------------------------------------------------------------------------
// Swin block, MI355X.
//   transpose weights -> bf16 (N x K)
//   LN1 (+roll+window gather) -> h bf16 [M][512]
//   gemm8 qkv  (256^2 8-phase)          -> qkv bf16 [M][1536]
//   attention (1 wave / window-head)    -> attno bf16 [M][512]
//   gemm8 proj (+unroll/unshift+resid)  -> y fp32 in d_out
//   LN2 -> h2 bf16
//   gemm8 mlp1 (+GELU)                  -> hid bf16 [M][2048] (aliases qkv)
//   gemm8 mlp2 (+resid)                 -> d_out fp32
// GEMM: 256x256 tile, BK=64, 8 waves (2Mx4N), dbuf LDS 128 KiB, counted
// vmcnt(2), per-phase barriers+setprio, XOR-swizzled LDS (row&7)<<4,
// XCD-chunked block swizzle.
// ---------------------------------------------------------------------------

using s8v = __attribute__((ext_vector_type(8))) short;   // 8 x bf16
using f4v = __attribute__((ext_vector_type(4))) float;   // MFMA acc

__device__ __forceinline__ short f2bf(float f) {
  union { __hip_bfloat16 h; short s; } u;
  u.h = __float2bfloat16(f);
  return u.s;
}
__device__ __forceinline__ f4v mfma16(s8v a, s8v b, f4v c) {
  return __builtin_amdgcn_mfma_f32_16x16x32_bf16(a, b, c, 0, 0, 0);
}
__device__ __forceinline__ f4v zero_f4() {
  f4v z; z[0] = 0.f; z[1] = 0.f; z[2] = 0.f; z[3] = 0.f; return z;
}
__device__ __forceinline__ s8v zero_s8() {
  s8v z;
#pragma unroll
  for (int i = 0; i < 8; ++i) z[i] = 0;
  return z;
}

// ---------------------------------------------------------------------------
__global__ __launch_bounds__(256) void transpose_w(const float* __restrict__ in,
                                                   short* __restrict__ outT,
                                                   int K, int N) {
  int idx = blockIdx.x * 256 + threadIdx.x;
  if (idx >= K * N) return;
  int k = idx / N, n = idx - k * N;
  outT[(size_t)n * K + k] = f2bf(in[idx]);
}

// ---------------------------------------------------------------------------
__global__ __launch_bounds__(256) void ln_kernel(const float* __restrict__ xin,
                                                 const float* __restrict__ g,
                                                 const float* __restrict__ bt,
                                                 short* __restrict__ outh,
                                                 int gather) {
  const int wid = threadIdx.x >> 6, lane = threadIdx.x & 63;
  const int m = blockIdx.x * 4 + wid;
  size_t src;
  if (gather) {
    int w = m / 49, n = m - w * 49;
    int b = w >> 6, wh = (w >> 3) & 7, ww = w & 7;
    int i = n / 7, j = n - i * 7;
    int r = wh * 7 + i + 3; if (r >= 56) r -= 56;
    int c = ww * 7 + j + 3; if (c >= 56) c -= 56;
    src = (size_t)b * 3136 + r * 56 + c;
  } else {
    src = m;
  }
  const float4* xp = (const float4*)(xin + src * 512) + lane * 2;
  float4 u0 = xp[0], u1 = xp[1];
  float vs[8] = {u0.x, u0.y, u0.z, u0.w, u1.x, u1.y, u1.z, u1.w};
  float s = 0.f;
#pragma unroll
  for (int e = 0; e < 8; ++e) s += vs[e];
#pragma unroll
  for (int msk = 1; msk < 64; msk <<= 1) s += __shfl_xor(s, msk, 64);
  const float mean = s * (1.0f / 512.0f);
  float ss = 0.f;
#pragma unroll
  for (int e = 0; e < 8; ++e) { float d = vs[e] - mean; ss += d * d; }
#pragma unroll
  for (int msk = 1; msk < 64; msk <<= 1) ss += __shfl_xor(ss, msk, 64);
  const float rstd = rsqrtf(ss * (1.0f / 512.0f) + 1e-5f);
  const float4* gp = (const float4*)g + lane * 2;
  const float4* bp = (const float4*)bt + lane * 2;
  float4 g0 = gp[0], g1 = gp[1], b0 = bp[0], b1 = bp[1];
  float gs[8] = {g0.x, g0.y, g0.z, g0.w, g1.x, g1.y, g1.z, g1.w};
  float bs[8] = {b0.x, b0.y, b0.z, b0.w, b1.x, b1.y, b1.z, b1.w};
  s8v o;
#pragma unroll
  for (int e = 0; e < 8; ++e) o[e] = f2bf((vs[e] - mean) * rstd * gs[e] + bs[e]);
  *(s8v*)(outh + (size_t)m * 512 + lane * 8) = o;
}

// ---------------------------------------------------------------------------
// 256x256 8-phase GEMM. A[M][K] bf16, BT[N][K] bf16.
// EPI: 0=qkv(bias->bf16) 1=proj(bias+unwindow+unshift+residual->fp32)
//      2=gelu(bias+erf gelu->bf16) 3=res(bias+residual->fp32)
// LDS swizzle: within each 128-B LDS row, 16-B slot index ^= (row&7).
// Staging (global_load_lds writes linearly) uses the inverse swizzle on the
// global source column: col = ((lane&7)^(lane>>3))*8  [row&7 == lane>>3].
// ---------------------------------------------------------------------------
template <int EPI>
__global__ __launch_bounds__(512, 2) void gemm8(const short* __restrict__ A,
                                                const short* __restrict__ BT,
                                                const float* __restrict__ bias,
                                                short* __restrict__ outb,
                                                const float* __restrict__ resid,
                                                float* __restrict__ outf,
                                                int K, int N, int NBC) {
  __shared__ short As[2][2][128 * 64];  // [dbuf][half][row*64+col] 64 KiB
  __shared__ short Bs[2][2][128 * 64];  // 64 KiB
  const int tid = threadIdx.x;
  const int wid = tid >> 6, lane = tid & 63;
  const int lr = lane & 15, hi = lane >> 4;
  const int wr = wid >> 2, wc = wid & 3;  // wave tile: rows wr*128, cols wc*64

  // XCD-chunked bijective swizzle (gridDim.x divisible by 8)
  const int cpx = gridDim.x >> 3;
  const int flat = blockIdx.x;
  const int swz = (flat & 7) * cpx + (flat >> 3);
  const int bcol = swz % NBC, brow = swz / NBC;

  // staging: half-tile = 128 rows x 64 cols of one tensor = 16 KiB
  // per thread 2 loads l={0,1}: dest short = l*4096 + wid*512 (+ lane*8 by HW)
  // source row r = l*64 + wid*8 + (lane>>3); swizzled col below.
  const int srow_lo = wid * 8 + (lane >> 3);
  const int scol_sw = ((lane & 7) ^ (lane >> 3)) * 8;

  const short* Abase = A + (size_t)(brow * 256) * K;
  const short* Bbase = BT + (size_t)(bcol * 256) * K;

  auto stage_half = [&](int tensor, int h, int t, int buf) {
    const short* gsrc = (tensor == 0 ? Abase : Bbase) +
                        (size_t)(h * 128) * K + t * 64 + scol_sw;
    short* ldst = (tensor == 0 ? &As[buf][h][0] : &Bs[buf][h][0]);
#pragma unroll
    for (int l = 0; l < 2; ++l) {
      __builtin_amdgcn_global_load_lds(
          (const __attribute__((address_space(1))) void*)(gsrc + (size_t)(l * 64 + srow_lo) * K),
          (__attribute__((address_space(3))) void*)(ldst + l * 4096 + wid * 512), 16, 0, 0);
    }
  };

  auto lda = [&](int buf, int mi, int ks) -> s8v {
    const int row = mi * 16 + lr;
    const int slot = (ks * 4 + hi) ^ (lr & 7);
    return *(const s8v*)((const char*)&As[buf][wr][0] + row * 128 + slot * 16);
  };
  auto ldb = [&](int buf, int ni, int ks) -> s8v {
    const int row = (wc & 1) * 64 + ni * 16 + lr;
    const int slot = (ks * 4 + hi) ^ (lr & 7);
    return *(const s8v*)((const char*)&Bs[buf][wc >> 1][0] + row * 128 + slot * 16);
  };

  f4v acc[8][4];
#pragma unroll
  for (int a = 0; a < 8; ++a)
#pragma unroll
    for (int b = 0; b < 4; ++b) acc[a][b] = zero_f4();

  // prologue: stage tile 0 -> buf 0 (8 vmem ops)
#pragma unroll
  for (int ht = 0; ht < 4; ++ht) stage_half(ht >> 1, ht & 1, 0, 0);

  const int NT = K >> 6;
  s8v bfrag[4];

  for (int t = 0; t < NT - 1; ++t) {
    const int buf = t & 1;
#pragma unroll
    for (int p = 0; p < 4; ++p) {
      const int ks = p >> 1, mh = p & 1;
      stage_half(p >> 1, p & 1, t + 1, buf ^ 1);  // 2 vmem ops
      if (p == 0) asm volatile("s_waitcnt vmcnt(2)" ::: "memory");
      __builtin_amdgcn_s_barrier();
      if (mh == 0) {
#pragma unroll
        for (int ni = 0; ni < 4; ++ni) bfrag[ni] = ldb(buf, ni, ks);
      }
      s8v af[4];
#pragma unroll
      for (int m = 0; m < 4; ++m) af[m] = lda(buf, mh * 4 + m, ks);
      __builtin_amdgcn_s_setprio(1);
#pragma unroll
      for (int m = 0; m < 4; ++m)
#pragma unroll
        for (int ni = 0; ni < 4; ++ni)
          acc[mh * 4 + m][ni] = mfma16(af[m], bfrag[ni], acc[mh * 4 + m][ni]);
      __builtin_amdgcn_s_setprio(0);
      __builtin_amdgcn_s_barrier();
    }
  }

  {  // epilogue tile (no staging)
    const int buf = (NT - 1) & 1;
#pragma unroll
    for (int p = 0; p < 4; ++p) {
      const int ks = p >> 1, mh = p & 1;
      if (p == 0) asm volatile("s_waitcnt vmcnt(0)" ::: "memory");
      __builtin_amdgcn_s_barrier();
      if (mh == 0) {
#pragma unroll
        for (int ni = 0; ni < 4; ++ni) bfrag[ni] = ldb(buf, ni, ks);
      }
      s8v af[4];
#pragma unroll
      for (int m = 0; m < 4; ++m) af[m] = lda(buf, mh * 4 + m, ks);
      __builtin_amdgcn_s_setprio(1);
#pragma unroll
      for (int m = 0; m < 4; ++m)
#pragma unroll
        for (int ni = 0; ni < 4; ++ni)
          acc[mh * 4 + m][ni] = mfma16(af[m], bfrag[ni], acc[mh * 4 + m][ni]);
      __builtin_amdgcn_s_setprio(0);
      __builtin_amdgcn_s_barrier();
    }
  }

  // epilogue
#pragma unroll
  for (int mi = 0; mi < 8; ++mi) {
#pragma unroll
    for (int ni = 0; ni < 4; ++ni) {
      const int col = bcol * 256 + wc * 64 + ni * 16 + lr;
      const float bv = bias[col];
      f4v v = acc[mi][ni];
#pragma unroll
      for (int j = 0; j < 4; ++j) {
        const int row = brow * 256 + wr * 128 + mi * 16 + hi * 4 + j;
        float val = v[j] + bv;
        if constexpr (EPI == 0) {
          outb[(size_t)row * N + col] = f2bf(val);
        } else if constexpr (EPI == 1) {
          int w = row / 49, n = row - w * 49;
          int b = w >> 6, wh = (w >> 3) & 7, ww = w & 7;
          int ii = n / 7, jj = n - ii * 7;
          int r = wh * 7 + ii + 3; if (r >= 56) r -= 56;
          int c = ww * 7 + jj + 3; if (c >= 56) c -= 56;
          size_t tok = (size_t)b * 3136 + r * 56 + c;
          outf[tok * 512 + col] = resid[tok * 512 + col] + val;
        } else if constexpr (EPI == 2) {
          float gv = 0.5f * val * (1.0f + erff(val * 0.70710678118654752f));
          outb[(size_t)row * N + col] = f2bf(gv);
        } else {
          outf[(size_t)row * 512 + col] = resid[(size_t)row * 512 + col] + val;
        }
      }
    }
  }
}

// ---------------------------------------------------------------------------
// Window attention: one wave per (window, head). N=49 padded to 64.
// ---------------------------------------------------------------------------
__device__ __forceinline__ int regof(int v) { return (v < 49) ? 0 : ((v < 53) ? 1 : 2); }

__global__ __launch_bounds__(64) void attn_kernel(const short* __restrict__ qkv,
                                                  const float* __restrict__ btab,
                                                  short* __restrict__ attno) {
  __shared__ short P[64 * 72];
  __shared__ short Vt[32 * 72];
  const int lane = threadIdx.x;
  const int w = blockIdx.x >> 4, head = blockIdx.x & 15;
  const int wh = (w >> 3) & 7, ww = w & 7;
  const int lr = lane & 15, hi = lane >> 4;

  s8v qf[4], kf[4];
#pragma unroll
  for (int t = 0; t < 4; ++t) {
    int row = t * 16 + lr;
    qf[t] = zero_s8();
    kf[t] = zero_s8();
    if (row < 49) {
      const short* base = qkv + (size_t)(w * 49 + row) * 1536 + head * 32 + hi * 8;
      qf[t] = *(const s8v*)base;
      kf[t] = *(const s8v*)(base + 512);
    }
  }

  f4v s[4][4];
  const f4v zacc = zero_f4();
#pragma unroll
  for (int qt = 0; qt < 4; ++qt)
#pragma unroll
    for (int kt = 0; kt < 4; ++kt) s[qt][kt] = mfma16(qf[qt], kf[kt], zacc);

  const float scale = 0.17677669529663687f;
  int ki_[4], kj_[4], labk_[4], kvalid[4];
#pragma unroll
  for (int kt = 0; kt < 4; ++kt) {
    int k = kt * 16 + lr;
    kvalid[kt] = (k < 49);
    int ki = k / 7, kj = k - ki * 7;
    ki_[kt] = ki; kj_[kt] = kj;
    labk_[kt] = regof(wh * 7 + ki) * 3 + regof(ww * 7 + kj);
  }
#pragma unroll
  for (int qt = 0; qt < 4; ++qt) {
#pragma unroll
    for (int j = 0; j < 4; ++j) {
      int q = qt * 16 + hi * 4 + j;
      int qvalid = (q < 49);
      int qi = q / 7, qj = q - qi * 7;
      int labq = regof(wh * 7 + qi) * 3 + regof(ww * 7 + qj);
#pragma unroll
      for (int kt = 0; kt < 4; ++kt) {
        float val = s[qt][kt][j] * scale;
        if (qvalid && kvalid[kt]) {
          int idx = (qi - ki_[kt] + 6) * 13 + (qj - kj_[kt] + 6);
          val += btab[idx * 16 + head];
          if (labq != labk_[kt]) val -= 100.f;
        }
        if (!kvalid[kt]) val = -1e30f;
        s[qt][kt][j] = val;
      }
    }
  }

#pragma unroll
  for (int qt = 0; qt < 4; ++qt) {
#pragma unroll
    for (int j = 0; j < 4; ++j) {
      float mx = fmaxf(fmaxf(s[qt][0][j], s[qt][1][j]), fmaxf(s[qt][2][j], s[qt][3][j]));
#pragma unroll
      for (int msk = 1; msk < 16; msk <<= 1) mx = fmaxf(mx, __shfl_xor(mx, msk, 64));
      float p[4], sum = 0.f;
#pragma unroll
      for (int kt = 0; kt < 4; ++kt) { p[kt] = __expf(s[qt][kt][j] - mx); sum += p[kt]; }
#pragma unroll
      for (int msk = 1; msk < 16; msk <<= 1) sum += __shfl_xor(sum, msk, 64);
      float inv = 1.f / sum;
      int q = qt * 16 + hi * 4 + j;
#pragma unroll
      for (int kt = 0; kt < 4; ++kt) P[q * 72 + kt * 16 + lr] = f2bf(p[kt] * inv);
    }
  }

  for (int idx = lane; idx < 2048; idx += 64) {
    int key = idx >> 5, d = idx & 31;
    short v = 0;
    if (key < 49) v = qkv[(size_t)(w * 49 + key) * 1536 + 1024 + head * 32 + d];
    Vt[d * 72 + key] = v;
  }
  __syncthreads();

  f4v o[4][2];
#pragma unroll
  for (int at = 0; at < 4; ++at)
#pragma unroll
    for (int dt = 0; dt < 2; ++dt) o[at][dt] = zero_f4();
#pragma unroll
  for (int ks = 0; ks < 2; ++ks) {
    s8v pa[4], vb[2];
#pragma unroll
    for (int at = 0; at < 4; ++at)
      pa[at] = *(const s8v*)(P + (at * 16 + lr) * 72 + ks * 32 + hi * 8);
#pragma unroll
    for (int dt = 0; dt < 2; ++dt)
      vb[dt] = *(const s8v*)(Vt + (dt * 16 + lr) * 72 + ks * 32 + hi * 8);
#pragma unroll
    for (int at = 0; at < 4; ++at)
#pragma unroll
      for (int dt = 0; dt < 2; ++dt) o[at][dt] = mfma16(pa[at], vb[dt], o[at][dt]);
  }

#pragma unroll
  for (int at = 0; at < 4; ++at)
#pragma unroll
    for (int dt = 0; dt < 2; ++dt)
#pragma unroll
      for (int j = 0; j < 4; ++j) {
        int q = at * 16 + hi * 4 + j;
        if (q < 49)
          attno[(size_t)(w * 49 + q) * 512 + head * 32 + dt * 16 + lr] = f2bf(o[at][dt][j]);
      }
}

// ---------------------------------------------------------------------------
extern "C" void kernel_launch(void* const* d_in, const int* in_sizes, int n_in,
                              void* d_out, int out_size, void* d_ws, size_t ws_size,
                              hipStream_t stream) {
  const float* x      = (const float*)d_in[0];
  const float* w_qkv  = (const float*)d_in[1];
  const float* b_qkv  = (const float*)d_in[2];
  const float* w_proj = (const float*)d_in[3];
  const float* b_proj = (const float*)d_in[4];
  const float* btab   = (const float*)d_in[5];
  const float* ln1g   = (const float*)d_in[6];
  const float* ln1b   = (const float*)d_in[7];
  const float* ln2g   = (const float*)d_in[8];
  const float* ln2b   = (const float*)d_in[9];
  const float* w1     = (const float*)d_in[10];
  const float* b1     = (const float*)d_in[11];
  const float* w2     = (const float*)d_in[12];
  const float* b2     = (const float*)d_in[13];
  float* out = (float*)d_out;

  // workspace layout (bytes): see round-0 comment; peak 520,093,696
  char* ws = (char*)d_ws;
  short* wqkvT  = (short*)(ws + 0);
  short* wprojT = (short*)(ws + 1572864);
  short* w1T    = (short*)(ws + 2097152);
  short* w2T    = (short*)(ws + 4194304);
  short* bufH   = (short*)(ws + 6291456);
  short* qkvb   = (short*)(ws + 109051904);
  short* attno  = (short*)(ws + 417333248);
  short* hid    = qkvb;  // alias: qkv+attno dead when MLP1 writes hid

  transpose_w<<<dim3(3072), 256, 0, stream>>>(w_qkv, wqkvT, 512, 1536);
  transpose_w<<<dim3(1024), 256, 0, stream>>>(w_proj, wprojT, 512, 512);
  transpose_w<<<dim3(4096), 256, 0, stream>>>(w1, w1T, 512, 2048);
  transpose_w<<<dim3(4096), 256, 0, stream>>>(w2, w2T, 2048, 512);

  ln_kernel<<<dim3(25088), 256, 0, stream>>>(x, ln1g, ln1b, bufH, 1);
  // grids: (N/256)*(M/256); all divisible by 8 for the XCD swizzle
  gemm8<0><<<dim3(6 * 392), 512, 0, stream>>>(bufH, wqkvT, b_qkv, qkvb, nullptr, nullptr, 512, 1536, 6);
  attn_kernel<<<dim3(32768), 64, 0, stream>>>(qkvb, btab, attno);
  gemm8<1><<<dim3(2 * 392), 512, 0, stream>>>(attno, wprojT, b_proj, nullptr, x, out, 512, 512, 2);
  ln_kernel<<<dim3(25088), 256, 0, stream>>>(out, ln2g, ln2b, bufH, 0);
  gemm8<2><<<dim3(8 * 392), 512, 0, stream>>>(bufH, w1T, b1, hid, nullptr, nullptr, 512, 2048, 8);
  gemm8<3><<<dim3(2 * 392), 512, 0, stream>>>(hid, w2T, b2, nullptr, out, out, 2048, 512, 2);
}

// Round 6
// 2007.570 us; speedup vs baseline: 1.2417x; 1.2087x over previous
//
#include <hip/hip_runtime.h>
#include <hip/hip_bf16.h>
#include <cstdint>
#include <cstddef>

// ---------------------------------------------------------------------------
// Swin block, MI355X.  Round-5: 128x128 GEMM (m97 structure, max residency)
// + XOR-swizzled LDS (0 bank conflicts, proven round-4) + XCD-chunked block
// swizzle (L2 locality).  LN / attention unchanged.
// ---------------------------------------------------------------------------

using s8v = __attribute__((ext_vector_type(8))) short;   // 8 x bf16
using f4v = __attribute__((ext_vector_type(4))) float;   // MFMA acc

__device__ __forceinline__ short f2bf(float f) {
  union { __hip_bfloat16 h; short s; } u;
  u.h = __float2bfloat16(f);
  return u.s;
}
__device__ __forceinline__ f4v mfma16(s8v a, s8v b, f4v c) {
  return __builtin_amdgcn_mfma_f32_16x16x32_bf16(a, b, c, 0, 0, 0);
}
__device__ __forceinline__ f4v zero_f4() {
  f4v z; z[0] = 0.f; z[1] = 0.f; z[2] = 0.f; z[3] = 0.f; return z;
}
__device__ __forceinline__ s8v zero_s8() {
  s8v z;
#pragma unroll
  for (int i = 0; i < 8; ++i) z[i] = 0;
  return z;
}

// ---------------------------------------------------------------------------
__global__ __launch_bounds__(256) void transpose_w(const float* __restrict__ in,
                                                   short* __restrict__ outT,
                                                   int K, int N) {
  int idx = blockIdx.x * 256 + threadIdx.x;
  if (idx >= K * N) return;
  int k = idx / N, n = idx - k * N;
  outT[(size_t)n * K + k] = f2bf(in[idx]);
}

// ---------------------------------------------------------------------------
__global__ __launch_bounds__(256) void ln_kernel(const float* __restrict__ xin,
                                                 const float* __restrict__ g,
                                                 const float* __restrict__ bt,
                                                 short* __restrict__ outh,
                                                 int gather) {
  const int wid = threadIdx.x >> 6, lane = threadIdx.x & 63;
  const int m = blockIdx.x * 4 + wid;
  size_t src;
  if (gather) {
    int w = m / 49, n = m - w * 49;
    int b = w >> 6, wh = (w >> 3) & 7, ww = w & 7;
    int i = n / 7, j = n - i * 7;
    int r = wh * 7 + i + 3; if (r >= 56) r -= 56;
    int c = ww * 7 + j + 3; if (c >= 56) c -= 56;
    src = (size_t)b * 3136 + r * 56 + c;
  } else {
    src = m;
  }
  const float4* xp = (const float4*)(xin + src * 512) + lane * 2;
  float4 u0 = xp[0], u1 = xp[1];
  float vs[8] = {u0.x, u0.y, u0.z, u0.w, u1.x, u1.y, u1.z, u1.w};
  float s = 0.f;
#pragma unroll
  for (int e = 0; e < 8; ++e) s += vs[e];
#pragma unroll
  for (int msk = 1; msk < 64; msk <<= 1) s += __shfl_xor(s, msk, 64);
  const float mean = s * (1.0f / 512.0f);
  float ss = 0.f;
#pragma unroll
  for (int e = 0; e < 8; ++e) { float d = vs[e] - mean; ss += d * d; }
#pragma unroll
  for (int msk = 1; msk < 64; msk <<= 1) ss += __shfl_xor(ss, msk, 64);
  const float rstd = rsqrtf(ss * (1.0f / 512.0f) + 1e-5f);
  const float4* gp = (const float4*)g + lane * 2;
  const float4* bp = (const float4*)bt + lane * 2;
  float4 g0 = gp[0], g1 = gp[1], b0 = bp[0], b1 = bp[1];
  float gs[8] = {g0.x, g0.y, g0.z, g0.w, g1.x, g1.y, g1.z, g1.w};
  float bs[8] = {b0.x, b0.y, b0.z, b0.w, b1.x, b1.y, b1.z, b1.w};
  s8v o;
#pragma unroll
  for (int e = 0; e < 8; ++e) o[e] = f2bf((vs[e] - mean) * rstd * gs[e] + bs[e]);
  *(s8v*)(outh + (size_t)m * 512 + lane * 8) = o;
}

// ---------------------------------------------------------------------------
// 128x128 GEMM, BK=64, 4 waves (2x2 of 64x64), 32 KiB LDS single-buffer,
// global_load_lds w16, XOR-swizzled LDS, XCD-chunked 1-D grid.
// A[M][K] bf16, BT[N][K] bf16.
// LDS layout: row r (128B = 8 slots of 16B); global k-slot s stored at LDS
// slot s^(r&7).  Staging uses inverse swizzle on the global source column
// (source slot = (lane&7)^(lane>>3), row&7 = lane>>3).  ds_read_b128 at
// quarter-wave granularity -> 2-way max (free); measured 0 conflicts (r4).
// EPI: 0=qkv(bias->bf16) 1=proj(bias+unwindow+unshift+residual->fp32)
//      2=gelu(bias+erf gelu->bf16) 3=res(bias+residual->fp32)
// ---------------------------------------------------------------------------
template <int EPI>
__global__ __launch_bounds__(256) void gemm_bt(const short* __restrict__ A,
                                               const short* __restrict__ BT,
                                               const float* __restrict__ bias,
                                               short* __restrict__ outb,
                                               const float* __restrict__ resid,
                                               float* __restrict__ outf,
                                               int K, int N, int NBC) {
  __shared__ short As[128 * 64];
  __shared__ short Bs[128 * 64];
  const int tid = threadIdx.x;
  const int wid = tid >> 6, lane = tid & 63;
  const int lr = lane & 15, hi = lane >> 4;
  const int r0 = (wid >> 1) * 64, c0 = (wid & 1) * 64;

  // XCD-chunked bijective swizzle (gridDim.x divisible by 8)
  const int cpx = gridDim.x >> 3;
  const int flat = blockIdx.x;
  const int swz = (flat & 7) * cpx + (flat >> 3);
  const int bcol = swz % NBC, brow = swz / NBC;

  // staging addresses: chunk = wid*4+i covers rows chunk*8..chunk*8+7
  const int srow = lane >> 3;                       // 0..7 within chunk
  const int scol_sw = ((lane & 7) ^ srow) * 8;      // inverse-swizzled col

  const short* Ab = A + (size_t)(brow * 128) * K;
  const short* Bb = BT + (size_t)(bcol * 128) * K;

  f4v acc[4][4];
#pragma unroll
  for (int a = 0; a < 4; ++a)
#pragma unroll
    for (int b = 0; b < 4; ++b) acc[a][b] = zero_f4();

  for (int k0 = 0; k0 < K; k0 += 64) {
#pragma unroll
    for (int i = 0; i < 4; ++i) {
      const int chunk = wid * 4 + i;
      const int row = chunk * 8 + srow;
      __builtin_amdgcn_global_load_lds(
          (const __attribute__((address_space(1))) void*)(Ab + (size_t)row * K + k0 + scol_sw),
          (__attribute__((address_space(3))) void*)(As + chunk * 512), 16, 0, 0);
      __builtin_amdgcn_global_load_lds(
          (const __attribute__((address_space(1))) void*)(Bb + (size_t)row * K + k0 + scol_sw),
          (__attribute__((address_space(3))) void*)(Bs + chunk * 512), 16, 0, 0);
    }
    __syncthreads();
#pragma unroll
    for (int ks = 0; ks < 2; ++ks) {
      s8v af[4], bfr[4];
#pragma unroll
      for (int mi = 0; mi < 4; ++mi) {
        const int row = r0 + mi * 16 + lr;
        const int slot = (ks * 4 + hi) ^ (lr & 7);
        af[mi] = *(const s8v*)((const char*)As + row * 128 + slot * 16);
      }
#pragma unroll
      for (int ni = 0; ni < 4; ++ni) {
        const int row = c0 + ni * 16 + lr;
        const int slot = (ks * 4 + hi) ^ (lr & 7);
        bfr[ni] = *(const s8v*)((const char*)Bs + row * 128 + slot * 16);
      }
#pragma unroll
      for (int mi = 0; mi < 4; ++mi)
#pragma unroll
        for (int ni = 0; ni < 4; ++ni)
          acc[mi][ni] = mfma16(af[mi], bfr[ni], acc[mi][ni]);
    }
    __syncthreads();
  }

#pragma unroll
  for (int mi = 0; mi < 4; ++mi) {
#pragma unroll
    for (int ni = 0; ni < 4; ++ni) {
      const int col = bcol * 128 + c0 + ni * 16 + lr;
      const float bv = bias[col];
      f4v v = acc[mi][ni];
#pragma unroll
      for (int j = 0; j < 4; ++j) {
        const int row = brow * 128 + r0 + mi * 16 + hi * 4 + j;
        float val = v[j] + bv;
        if constexpr (EPI == 0) {
          outb[(size_t)row * N + col] = f2bf(val);
        } else if constexpr (EPI == 1) {
          int w = row / 49, n = row - w * 49;
          int b = w >> 6, wh = (w >> 3) & 7, ww = w & 7;
          int ii = n / 7, jj = n - ii * 7;
          int r = wh * 7 + ii + 3; if (r >= 56) r -= 56;
          int c = ww * 7 + jj + 3; if (c >= 56) c -= 56;
          size_t tok = (size_t)b * 3136 + r * 56 + c;
          outf[tok * 512 + col] = resid[tok * 512 + col] + val;
        } else if constexpr (EPI == 2) {
          float gv = 0.5f * val * (1.0f + erff(val * 0.70710678118654752f));
          outb[(size_t)row * N + col] = f2bf(gv);
        } else {
          outf[(size_t)row * 512 + col] = resid[(size_t)row * 512 + col] + val;
        }
      }
    }
  }
}

// ---------------------------------------------------------------------------
// Window attention: one wave per (window, head). N=49 padded to 64.
// ---------------------------------------------------------------------------
__device__ __forceinline__ int regof(int v) { return (v < 49) ? 0 : ((v < 53) ? 1 : 2); }

__global__ __launch_bounds__(64) void attn_kernel(const short* __restrict__ qkv,
                                                  const float* __restrict__ btab,
                                                  short* __restrict__ attno) {
  __shared__ short P[64 * 72];
  __shared__ short Vt[32 * 72];
  const int lane = threadIdx.x;
  const int w = blockIdx.x >> 4, head = blockIdx.x & 15;
  const int wh = (w >> 3) & 7, ww = w & 7;
  const int lr = lane & 15, hi = lane >> 4;

  s8v qf[4], kf[4];
#pragma unroll
  for (int t = 0; t < 4; ++t) {
    int row = t * 16 + lr;
    qf[t] = zero_s8();
    kf[t] = zero_s8();
    if (row < 49) {
      const short* base = qkv + (size_t)(w * 49 + row) * 1536 + head * 32 + hi * 8;
      qf[t] = *(const s8v*)base;
      kf[t] = *(const s8v*)(base + 512);
    }
  }

  f4v s[4][4];
  const f4v zacc = zero_f4();
#pragma unroll
  for (int qt = 0; qt < 4; ++qt)
#pragma unroll
    for (int kt = 0; kt < 4; ++kt) s[qt][kt] = mfma16(qf[qt], kf[kt], zacc);

  const float scale = 0.17677669529663687f;
  int ki_[4], kj_[4], labk_[4], kvalid[4];
#pragma unroll
  for (int kt = 0; kt < 4; ++kt) {
    int k = kt * 16 + lr;
    kvalid[kt] = (k < 49);
    int ki = k / 7, kj = k - ki * 7;
    ki_[kt] = ki; kj_[kt] = kj;
    labk_[kt] = regof(wh * 7 + ki) * 3 + regof(ww * 7 + kj);
  }
#pragma unroll
  for (int qt = 0; qt < 4; ++qt) {
#pragma unroll
    for (int j = 0; j < 4; ++j) {
      int q = qt * 16 + hi * 4 + j;
      int qvalid = (q < 49);
      int qi = q / 7, qj = q - qi * 7;
      int labq = regof(wh * 7 + qi) * 3 + regof(ww * 7 + qj);
#pragma unroll
      for (int kt = 0; kt < 4; ++kt) {
        float val = s[qt][kt][j] * scale;
        if (qvalid && kvalid[kt]) {
          int idx = (qi - ki_[kt] + 6) * 13 + (qj - kj_[kt] + 6);
          val += btab[idx * 16 + head];
          if (labq != labk_[kt]) val -= 100.f;
        }
        if (!kvalid[kt]) val = -1e30f;
        s[qt][kt][j] = val;
      }
    }
  }

#pragma unroll
  for (int qt = 0; qt < 4; ++qt) {
#pragma unroll
    for (int j = 0; j < 4; ++j) {
      float mx = fmaxf(fmaxf(s[qt][0][j], s[qt][1][j]), fmaxf(s[qt][2][j], s[qt][3][j]));
#pragma unroll
      for (int msk = 1; msk < 16; msk <<= 1) mx = fmaxf(mx, __shfl_xor(mx, msk, 64));
      float p[4], sum = 0.f;
#pragma unroll
      for (int kt = 0; kt < 4; ++kt) { p[kt] = __expf(s[qt][kt][j] - mx); sum += p[kt]; }
#pragma unroll
      for (int msk = 1; msk < 16; msk <<= 1) sum += __shfl_xor(sum, msk, 64);
      float inv = 1.f / sum;
      int q = qt * 16 + hi * 4 + j;
#pragma unroll
      for (int kt = 0; kt < 4; ++kt) P[q * 72 + kt * 16 + lr] = f2bf(p[kt] * inv);
    }
  }

  for (int idx = lane; idx < 2048; idx += 64) {
    int key = idx >> 5, d = idx & 31;
    short v = 0;
    if (key < 49) v = qkv[(size_t)(w * 49 + key) * 1536 + 1024 + head * 32 + d];
    Vt[d * 72 + key] = v;
  }
  __syncthreads();

  f4v o[4][2];
#pragma unroll
  for (int at = 0; at < 4; ++at)
#pragma unroll
    for (int dt = 0; dt < 2; ++dt) o[at][dt] = zero_f4();
#pragma unroll
  for (int ks = 0; ks < 2; ++ks) {
    s8v pa[4], vb[2];
#pragma unroll
    for (int at = 0; at < 4; ++at)
      pa[at] = *(const s8v*)(P + (at * 16 + lr) * 72 + ks * 32 + hi * 8);
#pragma unroll
    for (int dt = 0; dt < 2; ++dt)
      vb[dt] = *(const s8v*)(Vt + (dt * 16 + lr) * 72 + ks * 32 + hi * 8);
#pragma unroll
    for (int at = 0; at < 4; ++at)
#pragma unroll
      for (int dt = 0; dt < 2; ++dt) o[at][dt] = mfma16(pa[at], vb[dt], o[at][dt]);
  }

#pragma unroll
  for (int at = 0; at < 4; ++at)
#pragma unroll
    for (int dt = 0; dt < 2; ++dt)
#pragma unroll
      for (int j = 0; j < 4; ++j) {
        int q = at * 16 + hi * 4 + j;
        if (q < 49)
          attno[(size_t)(w * 49 + q) * 512 + head * 32 + dt * 16 + lr] = f2bf(o[at][dt][j]);
      }
}

// ---------------------------------------------------------------------------
extern "C" void kernel_launch(void* const* d_in, const int* in_sizes, int n_in,
                              void* d_out, int out_size, void* d_ws, size_t ws_size,
                              hipStream_t stream) {
  const float* x      = (const float*)d_in[0];
  const float* w_qkv  = (const float*)d_in[1];
  const float* b_qkv  = (const float*)d_in[2];
  const float* w_proj = (const float*)d_in[3];
  const float* b_proj = (const float*)d_in[4];
  const float* btab   = (const float*)d_in[5];
  const float* ln1g   = (const float*)d_in[6];
  const float* ln1b   = (const float*)d_in[7];
  const float* ln2g   = (const float*)d_in[8];
  const float* ln2b   = (const float*)d_in[9];
  const float* w1     = (const float*)d_in[10];
  const float* b1     = (const float*)d_in[11];
  const float* w2     = (const float*)d_in[12];
  const float* b2     = (const float*)d_in[13];
  float* out = (float*)d_out;

  // workspace layout (bytes): see round-0 comment; peak 520,093,696
  char* ws = (char*)d_ws;
  short* wqkvT  = (short*)(ws + 0);
  short* wprojT = (short*)(ws + 1572864);
  short* w1T    = (short*)(ws + 2097152);
  short* w2T    = (short*)(ws + 4194304);
  short* bufH   = (short*)(ws + 6291456);
  short* qkvb   = (short*)(ws + 109051904);
  short* attno  = (short*)(ws + 417333248);
  short* hid    = qkvb;  // alias: qkv+attno dead when MLP1 writes hid

  transpose_w<<<dim3(3072), 256, 0, stream>>>(w_qkv, wqkvT, 512, 1536);
  transpose_w<<<dim3(1024), 256, 0, stream>>>(w_proj, wprojT, 512, 512);
  transpose_w<<<dim3(4096), 256, 0, stream>>>(w1, w1T, 512, 2048);
  transpose_w<<<dim3(4096), 256, 0, stream>>>(w2, w2T, 2048, 512);

  ln_kernel<<<dim3(25088), 256, 0, stream>>>(x, ln1g, ln1b, bufH, 1);
  // 1-D grids = (N/128)*(M/128); all divisible by 8 for XCD chunking
  gemm_bt<0><<<dim3(12 * 784), 256, 0, stream>>>(bufH, wqkvT, b_qkv, qkvb, nullptr, nullptr, 512, 1536, 12);
  attn_kernel<<<dim3(32768), 64, 0, stream>>>(qkvb, btab, attno);
  gemm_bt<1><<<dim3(4 * 784), 256, 0, stream>>>(attno, wprojT, b_proj, nullptr, x, out, 512, 512, 4);
  ln_kernel<<<dim3(25088), 256, 0, stream>>>(out, ln2g, ln2b, bufH, 0);
  gemm_bt<2><<<dim3(16 * 784), 256, 0, stream>>>(bufH, w1T, b1, hid, nullptr, nullptr, 512, 2048, 16);
  gemm_bt<3><<<dim3(4 * 784), 256, 0, stream>>>(hid, w2T, b2, nullptr, out, out, 2048, 512, 4);
}